// Round 2
// baseline (758.766 us; speedup 1.0000x reference)
//
#include <hip/hip_runtime.h>

typedef short s16x8 __attribute__((ext_vector_type(8)));
typedef float f32x16 __attribute__((ext_vector_type(16)));
typedef float f32x4 __attribute__((ext_vector_type(4)));

__device__ __forceinline__ float bf2f(short s) {
  unsigned int u = ((unsigned int)(unsigned short)s) << 16;
  return __builtin_bit_cast(float, u);
}
__device__ __forceinline__ short f2bf(float f) {
  unsigned int u = __builtin_bit_cast(unsigned int, f);
  u += 0x7fffu + ((u >> 16) & 1u);   // RNE
  return (short)(u >> 16);
}

#define GEPS 1e-20f

// ---------------- dtype detector ----------------
// fp32 data read as bf16 shorts: low halves have uniform-random exponent bits
// (~44% have exp field >= 0x90, i.e. |v| >= 2^17). bf16 uniform(-1,1): exp <= 126.
__global__ __launch_bounds__(256) void k_detect(const short* __restrict__ cb,
                                                int* __restrict__ flag) {
  __shared__ int cnt[256];
  int c = 0;
#pragma unroll
  for (int i = 0; i < 64; ++i) {
    unsigned short v = (unsigned short)cb[threadIdx.x * 64 + i];
    if (((v >> 7) & 0xFF) >= 0x90) ++c;
  }
  cnt[threadIdx.x] = c;
  __syncthreads();
  for (int s = 128; s; s >>= 1) {
    if (threadIdx.x < (unsigned)s) cnt[threadIdx.x] += cnt[threadIdx.x + s];
    __syncthreads();
  }
  if (threadIdx.x == 0) flag[0] = (cnt[0] > 512) ? 1 : 0;
}

// ---------------- codebook prep ----------------
// Writes CBhiX/CBloX (B-frag order, n=v,k=d) and CTX (B-frag order, n=d,k=v).
// Frag order: elem(n,k) -> [(((n>>5)*64 + (k>>4))*2 + ((k>>3)&1))*256 + (n&31)*8 + (k&7)]
__device__ __forceinline__ int fragidx(int n, int k) {
  return ((((n >> 5) * 64 + (k >> 4)) * 2 + ((k >> 3) & 1)) << 8) + ((n & 31) << 3) + (k & 7);
}

__global__ __launch_bounds__(256) void k_prep(const void* __restrict__ cb,
                                              short* __restrict__ CBhiX,
                                              short* __restrict__ CBloX,
                                              short* __restrict__ CTX,
                                              const int* __restrict__ flag) {
  const int f32m = *flag;
  const int idx = blockIdx.x * 256 + threadIdx.x;   // 1M elements
  const int v = idx >> 10, d = idx & 1023;
  float val;
  if (f32m) val = ((const float*)cb)[idx];
  else      val = bf2f(((const short*)cb)[idx]);
  short hi = f2bf(val);
  short lo = f2bf(val - bf2f(hi));
  CBhiX[fragidx(v, d)] = hi;
  CBloX[fragidx(v, d)] = lo;
  CTX[fragidx(d, v)]   = hi;
}

// ---------------- fused GVQ ----------------
// 512 thr = 8 waves; M=32 rows/block; wave w owns cols [128w,128w+128) (4 x 32x32 tiles).
__global__ __launch_bounds__(512, 2) void k_gvq(
    const void* __restrict__ Xv,
    const short* __restrict__ CBhiX,
    const short* __restrict__ CBloX,
    const short* __restrict__ CTX,
    const void* __restrict__ Gv,
    void* __restrict__ outv,
    const int* __restrict__ flag) {
  __shared__ short Ahi[32 * 1024];   // X-hi, later P (bf16), xor-swizzled 16B chunks
  __shared__ short Alo[32 * 1024];   // X-lo
  __shared__ float rmaxL[8][32];
  __shared__ float rsumL[8][32];
  __shared__ float rowMax[32];
  __shared__ float rowInv[32];

  const int f32m = *flag;
  const int tid = threadIdx.x;
  const int l   = tid & 63;
  const int w   = tid >> 6;
  const int ln  = l & 31;
  const int h   = l >> 5;
  const int r0  = blockIdx.x * 32;

  // ---- stage X (32x1024): split hi/lo bf16, chunk (m,g) stored at g^(m&7) ----
#pragma unroll
  for (int i = 0; i < 8; ++i) {
    int c = tid + i * 512;
    int m = c >> 7, g = c & 127;
    s16x8 hi, lo;
    if (f32m) {
      const float* xp = (const float*)Xv + (r0 + m) * 1024 + g * 8;
      f32x4 a = *(const f32x4*)xp;
      f32x4 b = *(const f32x4*)(xp + 4);
#pragma unroll
      for (int j = 0; j < 8; ++j) {
        float v = (j < 4) ? a[j] : b[j - 4];
        hi[j] = f2bf(v);
        lo[j] = f2bf(v - bf2f(hi[j]));
      }
    } else {
      hi = *(const s16x8*)((const short*)Xv + (r0 + m) * 1024 + g * 8);
#pragma unroll
      for (int j = 0; j < 8; ++j) lo[j] = 0;
    }
    *(s16x8*)&Ahi[m * 1024 + ((g ^ (m & 7)) << 3)] = hi;
    *(s16x8*)&Alo[m * 1024 + ((g ^ (m & 7)) << 3)] = lo;
  }
  __syncthreads();

  f32x16 acc[4];
#pragma unroll
  for (int nt = 0; nt < 4; ++nt)
#pragma unroll
    for (int i = 0; i < 16; ++i) acc[nt][i] = 0.0f;

  // ---- GEMM1: logits = Xhi*Bhi + Xlo*Bhi + Xhi*Blo ----
  {
    const short* bh = CBhiX + (w * 4) * 32768 + h * 256 + ln * 8;
    const short* bl = CBloX + (w * 4) * 32768 + h * 256 + ln * 8;
    const short* ap = &Ahi[ln * 1024];
    const short* al = &Alo[ln * 1024];
    const int sw = ln & 7;
    for (int ks = 0; ks < 64; ++ks) {
      const int ao = ((2 * ks + h) ^ sw) << 3;
      s16x8 ahi = *(const s16x8*)(ap + ao);
      s16x8 alo = *(const s16x8*)(al + ao);
#pragma unroll
      for (int nt = 0; nt < 4; ++nt) {
        s16x8 bhv = *(const s16x8*)(bh + nt * 32768 + ks * 512);
        s16x8 blv = *(const s16x8*)(bl + nt * 32768 + ks * 512);
        acc[nt] = __builtin_amdgcn_mfma_f32_32x32x16_bf16(ahi, bhv, acc[nt], 0, 0, 0);
        acc[nt] = __builtin_amdgcn_mfma_f32_32x32x16_bf16(alo, bhv, acc[nt], 0, 0, 0);
        acc[nt] = __builtin_amdgcn_mfma_f32_32x32x16_bf16(ahi, blv, acc[nt], 0, 0, 0);
      }
    }
  }

  // ---- gumbel + /T; per-row max. C/D: row=(r&3)+8*(r>>2)+4h, col=ln ----
  float pmax[16];
#pragma unroll
  for (int r = 0; r < 16; ++r) pmax[r] = -3.0e38f;
#pragma unroll
  for (int nt = 0; nt < 4; ++nt) {
    const int c = w * 128 + nt * 32 + ln;
    float ur[16];
    if (f32m) {
      const float* gp = (const float*)Gv + r0 * 1024 + c;
#pragma unroll
      for (int r = 0; r < 16; ++r) {
        const int rho = (r & 3) + 8 * (r >> 2) + 4 * h;
        ur[r] = gp[rho * 1024];
      }
    } else {
      const short* gp = (const short*)Gv + r0 * 1024 + c;
#pragma unroll
      for (int r = 0; r < 16; ++r) {
        const int rho = (r & 3) + 8 * (r >> 2) + 4 * h;
        ur[r] = bf2f(gp[rho * 1024]);
      }
    }
#pragma unroll
    for (int r = 0; r < 16; ++r) {
      float gvn = -__logf(-__logf(ur[r] + GEPS) + GEPS);
      float y = (acc[nt][r] + gvn) * 2.0f;
      acc[nt][r] = y;
      pmax[r] = fmaxf(pmax[r], y);
    }
  }
#pragma unroll
  for (int off = 16; off; off >>= 1)
#pragma unroll
    for (int r = 0; r < 16; ++r)
      pmax[r] = fmaxf(pmax[r], __shfl_xor(pmax[r], off, 64));
  if (ln == 0) {
#pragma unroll
    for (int r = 0; r < 16; ++r)
      rmaxL[w][(r & 3) + 8 * (r >> 2) + 4 * h] = pmax[r];
  }
  __syncthreads();
  if (tid < 32) {
    float m = rmaxL[0][tid];
#pragma unroll
    for (int j = 1; j < 8; ++j) m = fmaxf(m, rmaxL[j][tid]);
    rowMax[tid] = m;
  }
  __syncthreads();

  // ---- exp + per-row sum ----
  float psum[16];
#pragma unroll
  for (int r = 0; r < 16; ++r) psum[r] = 0.0f;
#pragma unroll
  for (int nt = 0; nt < 4; ++nt) {
#pragma unroll
    for (int r = 0; r < 16; ++r) {
      const int rho = (r & 3) + 8 * (r >> 2) + 4 * h;
      float e = __expf(acc[nt][r] - rowMax[rho]);
      acc[nt][r] = e;
      psum[r] += e;
    }
  }
#pragma unroll
  for (int off = 16; off; off >>= 1)
#pragma unroll
    for (int r = 0; r < 16; ++r)
      psum[r] += __shfl_xor(psum[r], off, 64);
  if (ln == 0) {
#pragma unroll
    for (int r = 0; r < 16; ++r)
      rsumL[w][(r & 3) + 8 * (r >> 2) + 4 * h] = psum[r];
  }
  __syncthreads();
  if (tid < 32) {
    float s = rsumL[0][tid];
#pragma unroll
    for (int j = 1; j < 8; ++j) s += rsumL[j][tid];
    rowInv[tid] = 1.0f / s;
  }
  __syncthreads();

  // ---- P: scatter bf16 to LDS (A-layout for GEMM2) + store soft_one_hot ----
  float* outQf = (float*)outv;
  float* outPf = outQf + 33554432;
  short* outQs = (short*)outv;
  short* outPs = outQs + 33554432;
#pragma unroll
  for (int nt = 0; nt < 4; ++nt) {
    const int c = w * 128 + nt * 32 + ln;
    const int g = c >> 3, cs = c & 7;
#pragma unroll
    for (int r = 0; r < 16; ++r) {
      const int rho = (r & 3) + 8 * (r >> 2) + 4 * h;
      float p = acc[nt][r] * rowInv[rho];
      Ahi[rho * 1024 + ((g ^ (rho & 7)) << 3) + cs] = f2bf(p);
      if (f32m) outPf[(r0 + rho) * 1024 + c] = p;
      else      outPs[(r0 + rho) * 1024 + c] = f2bf(p);
    }
  }
  __syncthreads();   // P visible to all waves

  // ---- GEMM2: Q = P @ CB  (B = CTX, n = output dim d) ----
#pragma unroll
  for (int nt = 0; nt < 4; ++nt)
#pragma unroll
    for (int i = 0; i < 16; ++i) acc[nt][i] = 0.0f;
  {
    const short* bt = CTX + (w * 4) * 32768 + h * 256 + ln * 8;
    const short* ap = &Ahi[ln * 1024];
    const int sw = ln & 7;
    for (int ks = 0; ks < 64; ++ks) {
      s16x8 a = *(const s16x8*)(ap + (((2 * ks + h) ^ sw) << 3));
#pragma unroll
      for (int nt = 0; nt < 4; ++nt) {
        s16x8 b = *(const s16x8*)(bt + nt * 32768 + ks * 512);
        acc[nt] = __builtin_amdgcn_mfma_f32_32x32x16_bf16(a, b, acc[nt], 0, 0, 0);
      }
    }
  }

  // ---- store quantized direct from regs ----
#pragma unroll
  for (int nt = 0; nt < 4; ++nt) {
    const int c = w * 128 + nt * 32 + ln;
#pragma unroll
    for (int r = 0; r < 16; ++r) {
      const int rho = (r & 3) + 8 * (r >> 2) + 4 * h;
      float q = acc[nt][r];
      if (f32m) outQf[(r0 + rho) * 1024 + c] = q;
      else      outQs[(r0 + rho) * 1024 + c] = f2bf(q);
    }
  }
}

extern "C" void kernel_launch(void* const* d_in, const int* in_sizes, int n_in,
                              void* d_out, int out_size, void* d_ws, size_t ws_size,
                              hipStream_t stream) {
  short* wss  = (short*)d_ws;
  short* CBhiX = wss;                  // 2 MB
  short* CBloX = wss + (1 << 20);      // 2 MB
  short* CTX   = wss + (2 << 20);      // 2 MB
  int*   flag  = (int*)(wss + (3 << 20));

  k_detect<<<1, 256, 0, stream>>>((const short*)d_in[1], flag);
  k_prep<<<4096, 256, 0, stream>>>(d_in[1], CBhiX, CBloX, CTX, flag);
  k_gvq<<<1024, 512, 0, stream>>>(d_in[0], CBhiX, CBloX, CTX, d_in[2], d_out, flag);
}